// Round 5
// baseline (101.161 us; speedup 1.0000x reference)
//
#include <hip/hip_runtime.h>

// Problem constants (match reference)
#define BB 4
#define CC 32
#define HH 64
#define WW 64
#define KK 64
#define PIX (HH * WW)      // 4096
#define NBC (BB * CC)      // 128 planes

#define LOG2E 1.4426950408889634f

// v_exp_f32 is natively exp2 -> with u pre-scaled by log2(e), exp(u*rf)
// is ONE transcendental.
static __device__ __forceinline__ float fexp2(float x) {
    return __builtin_amdgcn_exp2f(x);
}

// ---------------------------------------------------------------------------
// r0-r4 evidence: intra-kernel changes (ops r2, vectorization r3, occupancy
// r4) each moved <= 5us; the ~32us controllable residual is dominated by the
// two dependent launches (~10us overhead each) around short executions.
// This version is ONE regular launch, no workspace:
//   block = (bc, half): computes ALL 64 inv_k for its bc in LDS (phase-1
//   duplicated across the bc's two blocks: 1.5x total work on 2x blocks),
//   then phase-2 + 2x2 pool for its 32-row half plane.
//   grid = 256 blocks x 1024 thr -> 16 waves/CU on all 256 CUs.
// u plane staged in LDS once, pre-scaled by log2e; phase-2 reads u from LDS.
// ---------------------------------------------------------------------------
__global__ __launch_bounds__(1024) void rf_fused(
        const float* __restrict__ u,
        const float* __restrict__ rfs,
        float* __restrict__ out) {
    const int bc   = blockIdx.x >> 1;
    const int half = blockIdx.x & 1;
    const int t    = threadIdx.x;
    const int w    = t >> 6;                 // wave 0..15
    const int l    = t & 63;

    __shared__ float su[PIX];                // 16 KB u plane (prescaled)
    __shared__ float sld[KK];                // 64 inv values

    // stage u plane: 1024 float4 loads, one per thread
    {
        const float4* u4  = (const float4*)(u + (size_t)bc * PIX);
        float4*       su4 = (float4*)su;
        float4 v = u4[t];
        v.x *= LOG2E; v.y *= LOG2E; v.z *= LOG2E; v.w *= LOG2E;
        su4[t] = v;
    }
    __syncthreads();

    // phase 1: wave w computes k = 4w .. 4w+3 (all 64 k per block)
    {
        const float4* su4 = (const float4*)su;
        #pragma unroll
        for (int j = 0; j < 4; ++j) {
            const int k = w * 4 + j;
            const float4* r4 = (const float4*)(rfs + (size_t)k * PIX);
            float s = 0.f;
            #pragma unroll
            for (int i = 0; i < 16; ++i) {
                const float4 rv = r4[64 * i + l];
                const float4 uv = su4[64 * i + l];
                s += (rv.x > 0.f) ? fexp2(uv.x * rv.x) : 0.f;
                s += (rv.y > 0.f) ? fexp2(uv.y * rv.y) : 0.f;
                s += (rv.z > 0.f) ? fexp2(uv.z * rv.z) : 0.f;
                s += (rv.w > 0.f) ? fexp2(uv.w * rv.w) : 0.f;
            }
            #pragma unroll
            for (int off = 32; off > 0; off >>= 1)
                s += __shfl_xor(s, off, 64);
            if (l == 0) sld[k] = 1.f / (1.f + s);
        }
    }
    __syncthreads();

    // phase 2: wave w covers rows half*32 + {2w, 2w+1}; lanes 0..31 even
    // row, lanes 32..63 odd row; each lane owns a horizontal float2 pair.
    // Wave's rf read per k = 512 contiguous bytes. u comes from LDS.
    {
        const int row  = half * 32 + 2 * w + (l >> 5);
        const int col2 = l & 31;
        const int p    = row * 64 + 2 * col2;

        const float2 uv = *(const float2*)(su + p);   // prescaled
        const float* rp = rfs + p;

        float h0 = 0.f, h1 = 0.f;
        #pragma unroll 16
        for (int k = 0; k < KK; ++k) {
            const float2 rv = *(const float2*)(rp + (size_t)k * PIX);
            const float  fi = sld[k];
            h0 += ((rv.x > 0.f) ? fi : 0.f) * fexp2(uv.x * rv.x);
            h1 += ((rv.y > 0.f) ? fi : 0.f) * fexp2(uv.y * rv.y);
        }

        float v = fmaxf(h0, h1);                      // horizontal pool
        v = fmaxf(v, __shfl_xor(v, 32, 64));          // vertical pool
        if (l < 32) {
            const int por = half * 16 + w;            // pooled row 0..31
            out[(size_t)bc * (HH / 2) * (WW / 2) + por * 32 + col2] = v;
        }
    }
}

extern "C" void kernel_launch(void* const* d_in, const int* in_sizes, int n_in,
                              void* d_out, int out_size, void* d_ws, size_t ws_size,
                              hipStream_t stream) {
    const float* u   = (const float*)d_in[0];
    const float* rfs = (const float*)d_in[1];
    float* out       = (float*)d_out;

    rf_fused<<<NBC * 2, 1024, 0, stream>>>(u, rfs, out);
}

// Round 6
// 77.184 us; speedup vs baseline: 1.3106x; 1.3106x over previous
//
#include <hip/hip_runtime.h>

// Problem constants (match reference)
#define BB 4
#define CC 32
#define HH 64
#define WW 64
#define KK 64
#define PIX (HH * WW)      // 4096
#define NBC (BB * CC)      // 128 planes

#define LOG2E 1.4426950408889634f

static __device__ __forceinline__ float fexp2(float x) {
    return __builtin_amdgcn_exp2f(x);
}

// ---------------------------------------------------------------------------
// r5 counters: VALUBusy 26%, Occ 40%, HBM 9% -> latency-bound; launch
// overhead measured ~1-2us/launch (101.2 = 40.7 fill + 57.6 exec + ~2.5).
// Lever: wave-UNIFORM sparsity (r1's failure was divergent/ragged sparsity).
// Gaussian bands: sigma<7, thr 0.05 -> <=34 of 64 rows nonzero per k, and
// ~34 of 64 k's active per row-pair. Phase-1 iterates only the row band
// (in-chunk zero rows self-kill via the rv>0 select). Phase-2 iterates a
// per-row-pair active-k list, identical across lanes -> same coalescing as
// the 73.3us r0 kernel, half the trip count. Skipped terms were +0.f adds,
// so all sums are bit-identical to r0's.
// ---------------------------------------------------------------------------

// workspace meta layout (after inv[8192] floats)
#define OFF_INV   0
#define OFF_Y0    8192     // 64 ints
#define OFF_Y1    8256     // 64 ints
#define OFF_CNT   8320     // 32 ints
#define OFF_KLIST 8352     // 32*64 ints

// Prep: 96 one-wave blocks, no inter-block dependencies, reads 2 MB of L2.
//  b<64:  k=b. lane l scans row l (16 float4) -> row-active; ballot -> y0,y1.
//  b>=64: rp=b-64. lane l = k; scans rows 2rp,2rp+1 of plane l (32 float4);
//         ballot-compact active k's (ascending) into klist[rp], count cnt.
__global__ __launch_bounds__(64) void rf_prep(
        const float* __restrict__ rfs, float* __restrict__ ws) {
    int* y0    = (int*)(ws + OFF_Y0);
    int* y1    = (int*)(ws + OFF_Y1);
    int* cnt   = (int*)(ws + OFF_CNT);
    int* klist = (int*)(ws + OFF_KLIST);
    const int b = blockIdx.x;
    const int l = threadIdx.x & 63;

    if (b < KK) {
        const int k = b;
        const float4* r4 = (const float4*)(rfs + (size_t)k * PIX + l * WW);
        bool act = false;
        #pragma unroll
        for (int i = 0; i < 16; ++i) {
            const float4 v = r4[i];
            act = act || (v.x > 0.f) || (v.y > 0.f) || (v.z > 0.f) || (v.w > 0.f);
        }
        const unsigned long long m = __ballot(act);
        if (l == 0) {
            y0[k] = __ffsll((long long)m) - 1;
            y1[k] = 63 - __clzll((long long)m);
        }
    } else {
        const int rp = b - KK;
        const float4* r4 = (const float4*)(rfs + (size_t)l * PIX + rp * 128);
        bool act = false;
        #pragma unroll
        for (int i = 0; i < 32; ++i) {
            const float4 v = r4[i];
            act = act || (v.x > 0.f) || (v.y > 0.f) || (v.z > 0.f) || (v.w > 0.f);
        }
        const unsigned long long m = __ballot(act);
        if (act) {
            const int idx = (int)__popcll(m & ((1ull << l) - 1ull));
            klist[rp * 64 + idx] = l;
        }
        if (l == 0) cnt[rp] = (int)__popcll(m);
    }
}

// Phase 1: one WAVE per (bc,k), grid NBC*16 x 256 (r0 structure), but the
// chunk loop runs only over the k's row band: trip 16 -> ~9.6 avg.
__global__ __launch_bounds__(256) void rf_phase1(
        const float* __restrict__ u,
        const float* __restrict__ rfs,
        float* __restrict__ ws) {
    float*     inv = ws + OFF_INV;
    const int* y0  = (const int*)(ws + OFF_Y0);
    const int* y1  = (const int*)(ws + OFF_Y1);

    const int bc = blockIdx.x >> 4;
    const int kg = blockIdx.x & 15;
    const int t  = threadIdx.x;
    const int w  = t >> 6;
    const int l  = t & 63;

    __shared__ float su[PIX];    // 16 KB, prescaled by log2e
    {
        const float4* u4  = (const float4*)(u + (size_t)bc * PIX);
        float4*       su4 = (float4*)su;
        #pragma unroll
        for (int i = 0; i < 4; ++i) {
            float4 v = u4[t + 256 * i];
            v.x *= LOG2E; v.y *= LOG2E; v.z *= LOG2E; v.w *= LOG2E;
            su4[t + 256 * i] = v;
        }
    }
    __syncthreads();

    const int k  = kg * 4 + w;
    const int sk = __builtin_amdgcn_readfirstlane(k);
    const int c0 = y0[sk] >> 2;              // chunk = 4 rows = 256 px
    const int c1 = y1[sk] >> 2;

    const float4* r4  = (const float4*)(rfs + (size_t)sk * PIX);
    const float4* su4 = (const float4*)su;

    float s = 0.f;
    #pragma unroll 4
    for (int i = c0; i <= c1; ++i) {
        const float4 rv = r4[64 * i + l];
        const float4 uv = su4[64 * i + l];
        s += (rv.x > 0.f) ? fexp2(uv.x * rv.x) : 0.f;
        s += (rv.y > 0.f) ? fexp2(uv.y * rv.y) : 0.f;
        s += (rv.z > 0.f) ? fexp2(uv.z * rv.z) : 0.f;
        s += (rv.w > 0.f) ? fexp2(uv.w * rv.w) : 0.f;
    }
    #pragma unroll
    for (int off = 32; off > 0; off >>= 1)
        s += __shfl_xor(s, off, 64);

    if (l == 0) inv[bc * KK + k] = 1.f / (1.f + s);
}

// Phase 2: r0's exact structure (wave per (bc,row-pair), thread owns the
// vertical pixel pair, scalar rf loads, shfl pooling) but the k loop walks
// the row-pair's active list (trip 64 -> ~34 avg, wave-uniform). List and
// inv values staged per-wave in LDS (own row, no barrier needed).
__global__ __launch_bounds__(256) void rf_phase2(
        const float* __restrict__ u,
        const float* __restrict__ rfs,
        const float* __restrict__ ws,
        float* __restrict__ out) {
    const float* inv   = ws + OFF_INV;
    const int*   cnt   = (const int*)(ws + OFF_CNT);
    const int*   klist = (const int*)(ws + OFF_KLIST);

    __shared__ int   sko[4][64];
    __shared__ float sfi[4][64];

    const int bc = blockIdx.x >> 3;                          // 8 blocks per bc
    const int t  = threadIdx.x;
    const int w  = t >> 6;
    const int rp = (blockIdx.x & 7) * 4 + w;                 // row pair 0..31
    const int l  = t & 63;

    const int c = cnt[rp];
    if (l < c) {
        const int k = klist[rp * 64 + l];
        sko[w][l] = k * PIX;
        sfi[w][l] = inv[bc * KK + k];
    }

    const int pbase = rp * 128 + l;                          // row 2*rp, col l
    const float u0 = u[(size_t)bc * PIX + pbase] * LOG2E;
    const float u1 = u[(size_t)bc * PIX + pbase + 64] * LOG2E;
    const float* __restrict__ rfp = rfs + pbase;

    float h0 = 0.f, h1 = 0.f;
    #pragma unroll 4
    for (int s = 0; s < c; ++s) {
        const int   ko = sko[w][s];                          // LDS broadcast
        const float fi = sfi[w][s];
        const float r0 = rfp[ko];
        const float r1 = rfp[ko + 64];
        h0 += ((r0 > 0.f) ? fi : 0.f) * fexp2(u0 * r0);
        h1 += ((r1 > 0.f) ? fi : 0.f) * fexp2(u1 * r1);
    }

    const float v = fmaxf(h0, h1);
    const float o = fmaxf(v, __shfl_xor(v, 1, 64));
    if ((l & 1) == 0)
        out[(size_t)bc * (HH / 2) * (WW / 2) + rp * 32 + (l >> 1)] = o;
}

extern "C" void kernel_launch(void* const* d_in, const int* in_sizes, int n_in,
                              void* d_out, int out_size, void* d_ws, size_t ws_size,
                              hipStream_t stream) {
    const float* u   = (const float*)d_in[0];
    const float* rfs = (const float*)d_in[1];
    float* out       = (float*)d_out;
    float* ws        = (float*)d_ws;

    rf_prep  <<<KK + 32,  64,  0, stream>>>(rfs, ws);
    rf_phase1<<<NBC * 16, 256, 0, stream>>>(u, rfs, ws);
    rf_phase2<<<NBC * 8,  256, 0, stream>>>(u, rfs, ws, out);
}

// Round 7
// 76.941 us; speedup vs baseline: 1.3148x; 1.0032x over previous
//
#include <hip/hip_runtime.h>

// Problem constants (match reference)
#define BB 4
#define CC 32
#define HH 64
#define WW 64
#define KK 64
#define PIX (HH * WW)      // 4096
#define NBC (BB * CC)      // 128 planes

#define LOG2E 1.4426950408889634f

static __device__ __forceinline__ float fexp2(float x) {
    return __builtin_amdgcn_exp2f(x);
}

// ---------------------------------------------------------------------------
// r0-r6 A/B ledger:
//   phase-2 dense scalar 64-iter unroll-8 (r0)   : 73.3  <- undefeated
//   phase-2 float2 (r3) / 8-wave (r4) / klist(r6): all worse (+4..+9)
//     -> phase-2 is latency-bound on an AFFINE load stream; any reduction
//        in loads-in-flight or LDS-dependent addressing loses.
//   phase-1 banding: only lever never isolated (r6 bundled it with klist).
// This round = r0-exact phase-2 (+ free exp2 prescale) + banded phase-1
// + minimal 64-block prep (y0/y1 row bands only).
// ---------------------------------------------------------------------------

// workspace layout (floats)
#define OFF_INV 0          // 128*64
#define OFF_Y0  8192       // 64 ints
#define OFF_Y1  8256       // 64 ints

// Prep: 64 one-wave blocks. Block k: lane l scans row l (16 float4),
// ballot -> first/last active row of RF k.
__global__ __launch_bounds__(64) void rf_prep(
        const float* __restrict__ rfs, float* __restrict__ ws) {
    int* y0 = (int*)(ws + OFF_Y0);
    int* y1 = (int*)(ws + OFF_Y1);
    const int k = blockIdx.x;
    const int l = threadIdx.x & 63;

    const float4* r4 = (const float4*)(rfs + (size_t)k * PIX + l * WW);
    bool act = false;
    #pragma unroll
    for (int i = 0; i < 16; ++i) {
        const float4 v = r4[i];
        act = act || (v.x > 0.f) || (v.y > 0.f) || (v.z > 0.f) || (v.w > 0.f);
    }
    const unsigned long long m = __ballot(act);
    if (l == 0) {
        y0[k] = __ffsll((long long)m) - 1;
        y1[k] = 63 - __clzll((long long)m);
    }
}

// Phase 1: one WAVE per (bc,k), grid NBC*16 x 256. Chunk loop only over the
// k's row band (chunk = 4 rows): trip 16 -> ~9.6 avg. Addresses stay affine
// (c0 is an SGPR); in-chunk zero rows self-kill via the rv>0 select.
__global__ __launch_bounds__(256) void rf_phase1(
        const float* __restrict__ u,
        const float* __restrict__ rfs,
        float* __restrict__ ws) {
    float*     inv = ws + OFF_INV;
    const int* y0  = (const int*)(ws + OFF_Y0);
    const int* y1  = (const int*)(ws + OFF_Y1);

    const int bc = blockIdx.x >> 4;
    const int kg = blockIdx.x & 15;
    const int t  = threadIdx.x;
    const int w  = t >> 6;
    const int l  = t & 63;

    __shared__ float su[PIX];    // 16 KB, prescaled by log2e
    {
        const float4* u4  = (const float4*)(u + (size_t)bc * PIX);
        float4*       su4 = (float4*)su;
        #pragma unroll
        for (int i = 0; i < 4; ++i) {
            float4 v = u4[t + 256 * i];
            v.x *= LOG2E; v.y *= LOG2E; v.z *= LOG2E; v.w *= LOG2E;
            su4[t + 256 * i] = v;
        }
    }
    __syncthreads();

    const int k  = kg * 4 + w;
    const int sk = __builtin_amdgcn_readfirstlane(k);
    const int c0 = y0[sk] >> 2;              // chunk = 4 rows = 256 px
    const int c1 = y1[sk] >> 2;

    const float4* r4  = (const float4*)(rfs + (size_t)sk * PIX);
    const float4* su4 = (const float4*)su;

    float s = 0.f;
    #pragma unroll 4
    for (int i = c0; i <= c1; ++i) {
        const float4 rv = r4[64 * i + l];
        const float4 uv = su4[64 * i + l];
        s += (rv.x > 0.f) ? fexp2(uv.x * rv.x) : 0.f;
        s += (rv.y > 0.f) ? fexp2(uv.y * rv.y) : 0.f;
        s += (rv.z > 0.f) ? fexp2(uv.z * rv.z) : 0.f;
        s += (rv.w > 0.f) ? fexp2(uv.w * rv.w) : 0.f;
    }
    #pragma unroll
    for (int off = 32; off > 0; off >>= 1)
        s += __shfl_xor(s, off, 64);

    if (l == 0) inv[bc * KK + k] = 1.f / (1.f + s);
}

// Phase 2: r0-EXACT structure (undefeated): one WAVE per (bc,row-pair),
// 4096 waves, thread owns vertical pixel pair, 64 dense affine iters,
// unroll 8 -> 16 scalar loads in flight, wave-uniform inv via s_load,
// pooling in-register + one shfl. Only change vs r0: u prescaled once,
// exp2 instead of __expf (one fewer mul/element; proven neutral+safe).
__global__ __launch_bounds__(256) void rf_phase2(
        const float* __restrict__ u,
        const float* __restrict__ rfs,
        const float* __restrict__ ws,
        float* __restrict__ out) {
    const float* inv = ws + OFF_INV;

    const int bc = blockIdx.x >> 3;                          // 8 blocks per bc
    const int rp = (blockIdx.x & 7) * 4 + (threadIdx.x >> 6); // row pair 0..31
    const int l  = threadIdx.x & 63;

    const int pbase = rp * 128 + l;                          // row 2*rp, col l
    const float u0 = u[(size_t)bc * PIX + pbase] * LOG2E;
    const float u1 = u[(size_t)bc * PIX + pbase + 64] * LOG2E;
    const float* __restrict__ invp = inv + bc * KK;          // uniform base
    const float* __restrict__ rfp  = rfs + pbase;

    float h0 = 0.f, h1 = 0.f;
    #pragma unroll 8
    for (int k = 0; k < KK; ++k) {
        const float r0 = rfp[(size_t)k * PIX];
        const float r1 = rfp[(size_t)k * PIX + 64];
        const float fi = invp[k];                            // s_load (uniform)
        const float e0 = fexp2(u0 * r0);
        const float e1 = fexp2(u1 * r1);
        h0 += (r0 > 0.f) ? e0 * fi : 0.f;
        h1 += (r1 > 0.f) ? e1 * fi : 0.f;
    }

    // 2x2 pooling: vertical in-register, horizontal across lane pairs
    const float v = fmaxf(h0, h1);
    const float o = fmaxf(v, __shfl_xor(v, 1, 64));
    if ((l & 1) == 0)
        out[(size_t)bc * (HH / 2) * (WW / 2) + rp * 32 + (l >> 1)] = o;
}

extern "C" void kernel_launch(void* const* d_in, const int* in_sizes, int n_in,
                              void* d_out, int out_size, void* d_ws, size_t ws_size,
                              hipStream_t stream) {
    const float* u   = (const float*)d_in[0];
    const float* rfs = (const float*)d_in[1];
    float* out       = (float*)d_out;
    float* ws        = (float*)d_ws;

    rf_prep  <<<KK,       64,  0, stream>>>(rfs, ws);
    rf_phase1<<<NBC * 16, 256, 0, stream>>>(u, rfs, ws);
    rf_phase2<<<NBC * 8,  256, 0, stream>>>(u, rfs, ws, out);
}

// Round 8
// 73.636 us; speedup vs baseline: 1.3738x; 1.0449x over previous
//
#include <hip/hip_runtime.h>
#include <hip/hip_bf16.h>

// Problem constants (match reference)
#define BB 4
#define CC 32
#define HH 64
#define WW 64
#define KK 64
#define PIX (HH * WW)      // 4096
#define NBC (BB * CC)      // 128 planes

// ---------------------------------------------------------------------------
// r0 structure byte-exact (undefeated at 73.3us across 7 structural probes),
// with ONE isolated change: phase-2 unroll 8 -> 16. Evidence r0/r3/r4: time
// tracks (waves/SIMD) x (loads-in-flight/thread); this doubles the product
// (4 waves/SIMD x 32 scalar loads = 128 B/thread outstanding, 4 stall
// batches instead of 8). VGPR ~+32, still <= 128 (4 waves/SIMD preserved).
// ---------------------------------------------------------------------------

// Phase 1: one WAVE per (bc,k). 8192 waves, grid = NBC*16 blocks x 256 thr.
// u plane staged in LDS once per block (one barrier); rf read as float4 from
// L2 (rfs = 1 MB, L2-resident). Branchless masked sum, wave shuffle reduce.
__global__ __launch_bounds__(256) void rf_phase1(
        const float* __restrict__ u,
        const float* __restrict__ rfs,
        float* __restrict__ inv) {
    const int bc = blockIdx.x >> 4;
    const int kg = blockIdx.x & 15;
    const int t  = threadIdx.x;
    const int w  = t >> 6;
    const int l  = t & 63;

    __shared__ float su[PIX];    // 16 KB
    {
        const float4* u4  = (const float4*)(u + (size_t)bc * PIX);
        float4*       su4 = (float4*)su;
        #pragma unroll
        for (int i = 0; i < 4; ++i) su4[t + 256 * i] = u4[t + 256 * i];
    }
    __syncthreads();

    const int k = kg * 4 + w;
    const float4* r4  = (const float4*)(rfs + (size_t)k * PIX);
    const float4* su4 = (const float4*)su;

    float s = 0.f;
    #pragma unroll
    for (int i = 0; i < 16; ++i) {
        const float4 rv = r4[64 * i + l];
        const float4 uv = su4[64 * i + l];
        const float ex = __expf(uv.x * rv.x);
        const float ey = __expf(uv.y * rv.y);
        const float ez = __expf(uv.z * rv.z);
        const float ew = __expf(uv.w * rv.w);
        s += (rv.x > 0.f) ? ex : 0.f;
        s += (rv.y > 0.f) ? ey : 0.f;
        s += (rv.z > 0.f) ? ez : 0.f;
        s += (rv.w > 0.f) ? ew : 0.f;
    }
    #pragma unroll
    for (int off = 32; off > 0; off >>= 1)
        s += __shfl_xor(s, off, 64);

    if (l == 0) inv[bc * KK + k] = 1.f / (1.f + s);
}

// Phase 2: one WAVE per (bc, row-pair). 4096 waves, grid = NBC*8 x 256 thr.
// Thread l owns pixels (2*rp, l) and (2*rp+1, l). No LDS, no barriers;
// inv[k] is wave-uniform (bc from blockIdx only) -> scalar load. Pooling:
// vertical fmax in-register, horizontal fmax via shfl_xor(1).
// unroll 16: 32 scalar rf loads (128 B) outstanding per thread.
__global__ __launch_bounds__(256) void rf_phase2(
        const float* __restrict__ u,
        const float* __restrict__ rfs,
        const float* __restrict__ inv,
        float* __restrict__ out) {
    const int bc = blockIdx.x >> 3;                          // 8 blocks per bc
    const int rp = (blockIdx.x & 7) * 4 + (threadIdx.x >> 6); // row pair 0..31
    const int l  = threadIdx.x & 63;

    const int pbase = rp * 128 + l;                          // row 2*rp, col l
    const float u0 = u[(size_t)bc * PIX + pbase];
    const float u1 = u[(size_t)bc * PIX + pbase + 64];
    const float* __restrict__ invp = inv + bc * KK;          // uniform base
    const float* __restrict__ rfp  = rfs + pbase;

    float h0 = 0.f, h1 = 0.f;
    #pragma unroll 16
    for (int k = 0; k < KK; ++k) {
        const float r0 = rfp[(size_t)k * PIX];
        const float r1 = rfp[(size_t)k * PIX + 64];
        const float fi = invp[k];                            // s_load (uniform)
        const float e0 = __expf(u0 * r0);
        const float e1 = __expf(u1 * r1);
        h0 += (r0 > 0.f) ? e0 * fi : 0.f;
        h1 += (r1 > 0.f) ? e1 * fi : 0.f;
    }

    // 2x2 pooling: vertical in-register, horizontal across lane pairs
    const float v = fmaxf(h0, h1);
    const float o = fmaxf(v, __shfl_xor(v, 1, 64));
    if ((l & 1) == 0)
        out[(size_t)bc * (HH / 2) * (WW / 2) + rp * 32 + (l >> 1)] = o;
}

extern "C" void kernel_launch(void* const* d_in, const int* in_sizes, int n_in,
                              void* d_out, int out_size, void* d_ws, size_t ws_size,
                              hipStream_t stream) {
    const float* u   = (const float*)d_in[0];
    const float* rfs = (const float*)d_in[1];
    float* out       = (float*)d_out;
    float* inv       = (float*)d_ws;       // 128*64 floats = 32 KB scratch

    rf_phase1<<<NBC * 16, 256, 0, stream>>>(u, rfs, inv);
    rf_phase2<<<NBC * 8,  256, 0, stream>>>(u, rfs, inv, out);
}